// Round 1
// baseline (20341.039 us; speedup 1.0000x reference)
//
#include <hip/hip_runtime.h>
#include <hip/hip_bf16.h>
#include <math.h>

// Problem dims (fixed by setup_inputs): B=256, K(beams)=128, H=512, D=64, DEPTH=16
#define NB    256
#define NK    128
#define NH    512
#define ND    64
#define NDEPTH 16
#define BKROWS (NB*NK)          // 32768
#define TEMPD 20.0

// ---------------- init: states = root broadcast, scores = [0, -1e9...], hist = 0
__global__ void k_init(const float* __restrict__ root, float* __restrict__ states,
                       double* __restrict__ scores, int* __restrict__ hist) {
    int idx = blockIdx.x * 256 + threadIdx.x;          // 0 .. 16,777,215
    states[idx] = root[idx & (NH - 1)];
    if (idx < BKROWS) scores[idx] = ((idx & (NK - 1)) == 0) ? 0.0 : -1e9;
    if (idx < BKROWS * NDEPTH) hist[idx] = 0;
}

// ---------------- K1: logits = states @ W_logits + b ; logp = log_softmax(logits/20); cand = score + logp
// grid: BKROWS/32 = 1024 blocks, 256 threads. Block handles 32 rows x 64 decisions.
__global__ void k_logits(const float* __restrict__ states,
                         const float* __restrict__ Wl,      // [H][D] row-major
                         const float* __restrict__ bl,      // [D]
                         const double* __restrict__ scores, // [B*K]
                         double* __restrict__ cand)         // [B*K][D]
{
    __shared__ float s_tile[32][64];   // 8 KB
    __shared__ float w_tile[64][64];   // 16 KB
    const int rowb = blockIdx.x * 32;
    const int t    = threadIdx.x;
    const int lane = t & 63;           // decision d
    const int wv   = t >> 6;           // wave 0..3 -> rows wv*8 .. wv*8+7

    double acc[8];
    #pragma unroll
    for (int i = 0; i < 8; ++i) acc[i] = 0.0;

    for (int kc = 0; kc < NH; kc += 64) {
        for (int i = t; i < 64 * 64; i += 256) {
            int hh = i >> 6, dd = i & 63;
            w_tile[hh][dd] = Wl[(kc + hh) * ND + dd];
        }
        for (int i = t; i < 32 * 64; i += 256) {
            int r = i >> 6, hh = i & 63;
            s_tile[r][hh] = states[(size_t)(rowb + r) * NH + kc + hh];
        }
        __syncthreads();
        for (int hh = 0; hh < 64; ++hh) {
            double w = (double)w_tile[hh][lane];
            #pragma unroll
            for (int i = 0; i < 8; ++i)
                acc[i] = fma((double)s_tile[wv * 8 + i][hh], w, acc[i]);
        }
        __syncthreads();
    }

    const double bd = (double)bl[lane];
    #pragma unroll
    for (int i = 0; i < 8; ++i) {
        double x = (acc[i] + bd) / TEMPD;
        // wave-wide max over the 64 decisions of this row
        double m = x;
        for (int o = 32; o > 0; o >>= 1) m = fmax(m, __shfl_xor(m, o, 64));
        double e = exp(x - m);
        double s = e;
        for (int o = 32; o > 0; o >>= 1) s += __shfl_xor(s, o, 64);
        double logp = x - m - log(s);
        int row = rowb + wv * 8 + i;
        cand[(size_t)row * ND + lane] = scores[row] + logp;
    }
}

// ---------------- K2: per-batch top-128 of 8192 (value desc, index asc) + gather hist + write scores/parent/dec
// grid: 256 blocks (one per batch), 256 threads. Candidates held in registers (static indexing only).
__global__ void k_topk(const double* __restrict__ cand,    // [B][8192]
                       double* __restrict__ scores,        // [B*K] (new scores out)
                       int* __restrict__ parent, int* __restrict__ decs,
                       const int* __restrict__ hist_in, int* __restrict__ hist_out,
                       int tstep)
{
    __shared__ double sv[256];
    __shared__ int    si[256];
    __shared__ double bv; __shared__ int bi;
    __shared__ int sp[NK], sd[NK];

    const int b  = blockIdx.x;
    const int t0 = threadIdx.x;
    const double* cb = cand + (size_t)b * (NK * ND);

    double v[32];
    #pragma unroll
    for (int j = 0; j < 32; ++j) v[j] = cb[j * 256 + t0];   // slot index = j*256 + t0

    double mv = v[0]; int mi = t0;
    #pragma unroll
    for (int j = 1; j < 32; ++j) {
        int idx = j * 256 + t0;
        if (v[j] > mv) { mv = v[j]; mi = idx; }             // strict > keeps lowest index on ties
    }

    for (int it = 0; it < NK; ++it) {
        sv[t0] = mv; si[t0] = mi;
        __syncthreads();
        for (int s = 128; s > 0; s >>= 1) {
            if (t0 < s) {
                double v2 = sv[t0 + s]; int i2 = si[t0 + s];
                if (v2 > sv[t0] || (v2 == sv[t0] && i2 < si[t0])) { sv[t0] = v2; si[t0] = i2; }
            }
            __syncthreads();
        }
        if (t0 == 0) { bv = sv[0]; bi = si[0]; }
        __syncthreads();
        const int istar = bi; const double vstar = bv;
        if (t0 == 0) {
            int p = istar >> 6;        // / 64
            int d = istar & 63;        // % 64
            scores[b * NK + it] = vstar;
            parent[b * NK + it] = p;
            decs  [b * NK + it] = d;
            sp[it] = p; sd[it] = d;
        }
        if ((istar & 255) == t0) {     // this thread owns the extracted slot
            #pragma unroll
            for (int j = 0; j < 32; ++j) if (j * 256 + t0 == istar) v[j] = -INFINITY;
            mv = v[0]; mi = t0;
            #pragma unroll
            for (int j = 1; j < 32; ++j) if (v[j] > mv) { mv = v[j]; mi = j * 256 + t0; }
        }
        __syncthreads();
    }

    // hist gather: hist_out[b,k,:] = hist_in[b,parent[k],:]; [:,tstep] = dec
    for (int i = t0; i < NK * NDEPTH; i += 256) {
        int k = i >> 4, j = i & 15;
        int src = (b * NK + sp[k]) * NDEPTH + j;
        hist_out[(b * NK + k) * NDEPTH + j] = (j == tstep) ? sd[k] : hist_in[src];
    }
}

// ---------------- K3: new_states = tanh(states[parent] @ W_hh + b_hh + emb[dec]) ; fused gather
// grid: (BKROWS/32, 512/128) = (1024, 4), 256 threads. f64 accumulate.
__global__ void k_rnn(const float* __restrict__ states_in,
                      const float* __restrict__ Whh,   // [H][H] row-major
                      const float* __restrict__ bhh,   // [H]
                      const float* __restrict__ emb,   // [D][H]
                      const int* __restrict__ parent, const int* __restrict__ decs,
                      float* __restrict__ states_out)
{
    __shared__ float s_tile[32][64];    // 8 KB
    __shared__ float w_tile[64][128];   // 32 KB
    __shared__ int sp[32], sd[32];

    const int rowb = blockIdx.x * 32;
    const int colb = blockIdx.y * 128;
    const int t    = threadIdx.x;
    if (t < 32) { sp[t] = parent[rowb + t]; sd[t] = decs[rowb + t]; }
    __syncthreads();

    const int col = colb + (t & 127);
    const int rh  = (t >> 7) * 16;      // rows rh .. rh+15 (wave-uniform)

    double acc[16];
    #pragma unroll
    for (int i = 0; i < 16; ++i) acc[i] = 0.0;

    for (int kc = 0; kc < NH; kc += 64) {
        for (int i = t; i < 64 * 128; i += 256) {
            int hh = i >> 7, cc = i & 127;
            w_tile[hh][cc] = Whh[(size_t)(kc + hh) * NH + colb + cc];
        }
        for (int i = t; i < 32 * 64; i += 256) {
            int r = i >> 6, hh = i & 63;
            int batch = (rowb + r) >> 7;                 // row / 128
            s_tile[r][hh] = states_in[((size_t)batch * NK + sp[r]) * NH + kc + hh];
        }
        __syncthreads();
        for (int hh = 0; hh < 64; ++hh) {
            double w = (double)w_tile[hh][t & 127];
            #pragma unroll
            for (int i = 0; i < 16; ++i)
                acc[i] = fma((double)s_tile[rh + i][hh], w, acc[i]);
        }
        __syncthreads();
    }

    const double bb = (double)bhh[col];
    #pragma unroll
    for (int i = 0; i < 16; ++i) {
        int r = rh + i;
        double e = (double)emb[(size_t)sd[r] * NH + col];
        double z = acc[i] + bb + e;
        states_out[(size_t)(rowb + r) * NH + col] = (float)tanh(z);
    }
}

// ---------------- finalize: d_out = [hist as float (524288), scores as float (32768)]
__global__ void k_final(const int* __restrict__ hist, const double* __restrict__ scores,
                        float* __restrict__ out)
{
    int i = blockIdx.x * 256 + threadIdx.x;
    const int nh = BKROWS * NDEPTH;      // 524288
    if (i < nh) out[i] = (float)hist[i];
    else if (i < nh + BKROWS) out[i] = (float)scores[i - nh];
}

extern "C" void kernel_launch(void* const* d_in, const int* in_sizes, int n_in,
                              void* d_out, int out_size, void* d_ws, size_t ws_size,
                              hipStream_t stream) {
    // inputs: env(unused), root_state, W_logits, b_logits, W_hh, b_hh, emb, beams(scalar, =128)
    const float* root = (const float*)d_in[1];
    const float* Wl   = (const float*)d_in[2];
    const float* bl   = (const float*)d_in[3];
    const float* Whh  = (const float*)d_in[4];
    const float* bhh  = (const float*)d_in[5];
    const float* emb  = (const float*)d_in[6];

    // workspace layout (155,713,536 bytes total)
    char* ws = (char*)d_ws;
    double* cand   = (double*)(ws + 0);            // 32768*64*8  = 16,777,216
    double* scores = (double*)(ws + 16777216);     // 32768*8     =    262,144
    float*  sA     = (float*)(ws + 17039360);      // 32768*512*4 = 67,108,864
    float*  sB     = (float*)(ws + 84148224);      // 67,108,864
    int*    parent = (int*)(ws + 151257088);       // 131,072
    int*    decs   = (int*)(ws + 151388160);       // 131,072
    int*    hA     = (int*)(ws + 151519232);       // 2,097,152
    int*    hB     = (int*)(ws + 153616384);       // 2,097,152

    k_init<<<65536, 256, 0, stream>>>(root, sA, scores, hA);

    float* scur = sA; float* snxt = sB;
    int*   hcur = hA; int*   hnxt = hB;
    for (int t = 0; t < NDEPTH; ++t) {
        k_logits<<<1024, 256, 0, stream>>>(scur, Wl, bl, scores, cand);
        k_topk<<<256, 256, 0, stream>>>(cand, scores, parent, decs, hcur, hnxt, t);
        k_rnn<<<dim3(1024, 4), 256, 0, stream>>>(scur, Whh, bhh, emb, parent, decs, snxt);
        { float* tmp = scur; scur = snxt; snxt = tmp; }
        { int*   tmp = hcur; hcur = hnxt; hnxt = tmp; }
    }

    k_final<<<2176, 256, 0, stream>>>(hcur, scores, (float*)d_out);
}

// Round 2
// 12164.917 us; speedup vs baseline: 1.6721x; 1.6721x over previous
//
#include <hip/hip_runtime.h>
#include <hip/hip_bf16.h>
#include <math.h>

// Problem dims (fixed by setup_inputs): B=256, K(beams)=128, H=512, D=64, DEPTH=16
#define NB    256
#define NK    128
#define NH    512
#define ND    64
#define NDEPTH 16
#define BKROWS (NB*NK)          // 32768
#define TEMPD 20.0

// ---------------- init: states = root broadcast, scores = [0, -1e9...], hist = 0
__global__ void k_init(const float* __restrict__ root, float* __restrict__ states,
                       double* __restrict__ scores, int* __restrict__ hist) {
    int idx = blockIdx.x * 256 + threadIdx.x;          // 0 .. 16,777,215
    states[idx] = root[idx & (NH - 1)];
    if (idx < BKROWS) scores[idx] = ((idx & (NK - 1)) == 0) ? 0.0 : -1e9;
    if (idx < BKROWS * NDEPTH) hist[idx] = 0;
}

// ---------------- K1: logits GEMM (f64 acc) + log-softmax + cand = score + logp
// grid: 512 blocks (64 rows each), 256 threads. Thread: 8 rows x 2 cols (tc, tc+32).
__global__ void __launch_bounds__(256, 3)
k_logits(const float* __restrict__ states,
         const float* __restrict__ Wl,      // [H][D] row-major
         const float* __restrict__ bl,      // [D]
         const double* __restrict__ scores, // [B*K]
         double* __restrict__ cand)         // [B*K][D]
{
    __shared__ double wl[32][64];   // 16 KB
    __shared__ double st[64][32];   // 16 KB
    const int rowb = blockIdx.x * 64;
    const int t    = threadIdx.x;
    const int tc   = t & 31;
    const int rg   = t >> 5;

    double acc[8][2];
    #pragma unroll
    for (int i = 0; i < 8; ++i) { acc[i][0] = 0.0; acc[i][1] = 0.0; }

    for (int kc = 0; kc < NH; kc += 32) {
        #pragma unroll
        for (int j = 0; j < 2; ++j) {          // W tile: 32 x 64 = 512 float4
            int idx = t + 256 * j;
            int hh = idx >> 4, c4 = idx & 15;
            float4 v = *(const float4*)&Wl[(kc + hh) * ND + c4 * 4];
            wl[hh][c4*4+0] = (double)v.x; wl[hh][c4*4+1] = (double)v.y;
            wl[hh][c4*4+2] = (double)v.z; wl[hh][c4*4+3] = (double)v.w;
        }
        #pragma unroll
        for (int j = 0; j < 2; ++j) {          // S tile: 64 x 32 = 512 float4
            int idx = t + 256 * j;
            int r = idx >> 3, c4 = idx & 7;
            float4 v = *(const float4*)&states[(size_t)(rowb + r) * NH + kc + c4 * 4];
            st[r][c4*4+0] = (double)v.x; st[r][c4*4+1] = (double)v.y;
            st[r][c4*4+2] = (double)v.z; st[r][c4*4+3] = (double)v.w;
        }
        __syncthreads();
        #pragma unroll 4
        for (int hh = 0; hh < 32; hh += 2) {
            double w00 = wl[hh][tc],   w01 = wl[hh][tc+32];
            double w10 = wl[hh+1][tc], w11 = wl[hh+1][tc+32];
            #pragma unroll
            for (int i = 0; i < 8; ++i) {
                double2 s = *(const double2*)&st[rg*8+i][hh];
                acc[i][0] = fma(s.x, w00, acc[i][0]);
                acc[i][1] = fma(s.x, w01, acc[i][1]);
                acc[i][0] = fma(s.y, w10, acc[i][0]);
                acc[i][1] = fma(s.y, w11, acc[i][1]);
            }
        }
        __syncthreads();
    }

    const double bd0 = (double)bl[tc];
    const double bd1 = (double)bl[tc + 32];
    #pragma unroll
    for (int i = 0; i < 8; ++i) {
        int row = rowb + rg * 8 + i;
        double x0 = (acc[i][0] + bd0) / TEMPD;
        double x1 = (acc[i][1] + bd1) / TEMPD;
        // row max / sum across the 32 tc-threads (offsets 1..16 keep lanes in their half)
        double m = fmax(x0, x1);
        for (int off = 1; off <= 16; off <<= 1) m = fmax(m, __shfl_xor(m, off, 64));
        double e = exp(x0 - m) + exp(x1 - m);
        for (int off = 1; off <= 16; off <<= 1) e += __shfl_xor(e, off, 64);
        double ls = log(e);
        double sc = scores[row];
        cand[(size_t)row * ND + tc]      = sc + x0 - m - ls;
        cand[(size_t)row * ND + tc + 32] = sc + x1 - m - ls;
    }
}

// ---------------- K2: per-batch top-128 of 8192 (value desc, index asc) + hist gather
// grid: 256 blocks, 256 threads. Wave shfl reduce, 1 barrier/iter.
__global__ void k_topk(const double* __restrict__ cand,    // [B][8192]
                       double* __restrict__ scores,        // [B*K] (new scores out)
                       int* __restrict__ parent, int* __restrict__ decs,
                       const int* __restrict__ hist_in, int* __restrict__ hist_out,
                       int tstep)
{
    __shared__ double lv[2][4];
    __shared__ int    li[2][4];
    __shared__ int sp[NK], sd[NK];

    const int b    = blockIdx.x;
    const int t    = threadIdx.x;
    const int lane = t & 63;
    const int wv   = t >> 6;
    const double* cb = cand + (size_t)b * (NK * ND);

    double v[32];
    #pragma unroll
    for (int j = 0; j < 32; ++j) v[j] = cb[j * 256 + t];

    double mv = v[0]; int mi = t;
    #pragma unroll
    for (int j = 1; j < 32; ++j)
        if (v[j] > mv) { mv = v[j]; mi = j * 256 + t; }   // strict > keeps lowest idx

    for (int it = 0; it < NK; ++it) {
        const int p = it & 1;
        // wave-level reduce (value desc, index asc)
        double m = mv; int idx = mi;
        #pragma unroll
        for (int off = 1; off <= 32; off <<= 1) {
            double m2 = __shfl_xor(m, off, 64);
            int    i2 = __shfl_xor(idx, off, 64);
            if (m2 > m || (m2 == m && i2 < idx)) { m = m2; idx = i2; }
        }
        if (lane == 0) { lv[p][wv] = m; li[p][wv] = idx; }
        __syncthreads();
        double bm = lv[p][0]; int bi = li[p][0];
        #pragma unroll
        for (int w = 1; w < 4; ++w) {
            double m2 = lv[p][w]; int i2 = li[p][w];
            if (m2 > bm || (m2 == bm && i2 < bi)) { bm = m2; bi = i2; }
        }
        if (t == 0) {
            scores[b * NK + it] = bm;
            parent[b * NK + it] = bi >> 6;
            decs  [b * NK + it] = bi & 63;
            sp[it] = bi >> 6; sd[it] = bi & 63;
        }
        if ((bi & 255) == t) {            // owner extracts + rescans
            #pragma unroll
            for (int j = 0; j < 32; ++j) if (j * 256 + t == bi) v[j] = -INFINITY;
            mv = v[0]; mi = t;
            #pragma unroll
            for (int j = 1; j < 32; ++j)
                if (v[j] > mv) { mv = v[j]; mi = j * 256 + t; }
        }
    }
    __syncthreads();

    for (int i = t; i < NK * NDEPTH; i += 256) {
        int k = i >> 4, j = i & 15;
        hist_out[(b * NK + k) * NDEPTH + j] = (j == tstep) ? sd[k]
                                            : hist_in[(b * NK + sp[k]) * NDEPTH + j];
    }
}

// ---------------- K3: new_states = tanh(states[parent] @ W_hh + b_hh + emb[dec])
// grid: (512, 4), 256 threads. Block tile 64 rows x 128 cols; thread 8 rows x 4 cols.
__global__ void __launch_bounds__(256, 3)
k_rnn(const float* __restrict__ states_in,
      const float* __restrict__ Whh,   // [H][H] row-major
      const float* __restrict__ bhh,   // [H]
      const float* __restrict__ emb,   // [D][H]
      const int* __restrict__ parent, const int* __restrict__ decs,
      float* __restrict__ states_out)
{
    __shared__ double wt[32][128];   // 32 KB
    __shared__ double st[64][32];    // 16 KB
    __shared__ int sp[64], sd[64];

    const int rowb = blockIdx.x * 64;
    const int colb = blockIdx.y * 128;
    const int t    = threadIdx.x;
    const int tc   = t & 31;
    const int rg   = t >> 5;
    if (t < 64) { sp[t] = parent[rowb + t]; sd[t] = decs[rowb + t]; }
    __syncthreads();

    double acc[8][4];
    #pragma unroll
    for (int i = 0; i < 8; ++i)
        #pragma unroll
        for (int c = 0; c < 4; ++c) acc[i][c] = 0.0;

    for (int kc = 0; kc < NH; kc += 32) {
        #pragma unroll
        for (int j = 0; j < 4; ++j) {          // W tile: 32 x 128 = 1024 float4
            int idx = t + 256 * j;
            int hh = idx >> 5, c4 = idx & 31;
            float4 v = *(const float4*)&Whh[(size_t)(kc + hh) * NH + colb + c4 * 4];
            wt[hh][c4*4+0] = (double)v.x; wt[hh][c4*4+1] = (double)v.y;
            wt[hh][c4*4+2] = (double)v.z; wt[hh][c4*4+3] = (double)v.w;
        }
        #pragma unroll
        for (int j = 0; j < 2; ++j) {          // S tile (gathered): 64 x 32 = 512 float4
            int idx = t + 256 * j;
            int r = idx >> 3, c4 = idx & 7;
            int batch = (rowb + r) >> 7;
            float4 v = *(const float4*)&states_in[((size_t)batch * NK + sp[r]) * NH + kc + c4 * 4];
            st[r][c4*4+0] = (double)v.x; st[r][c4*4+1] = (double)v.y;
            st[r][c4*4+2] = (double)v.z; st[r][c4*4+3] = (double)v.w;
        }
        __syncthreads();
        #pragma unroll 2
        for (int hh = 0; hh < 32; hh += 2) {
            double w00 = wt[hh][tc],    w01 = wt[hh][tc+32],
                   w02 = wt[hh][tc+64], w03 = wt[hh][tc+96];
            double w10 = wt[hh+1][tc],    w11 = wt[hh+1][tc+32],
                   w12 = wt[hh+1][tc+64], w13 = wt[hh+1][tc+96];
            #pragma unroll
            for (int i = 0; i < 8; ++i) {
                double2 s = *(const double2*)&st[rg*8+i][hh];
                acc[i][0] = fma(s.x, w00, acc[i][0]);
                acc[i][1] = fma(s.x, w01, acc[i][1]);
                acc[i][2] = fma(s.x, w02, acc[i][2]);
                acc[i][3] = fma(s.x, w03, acc[i][3]);
                acc[i][0] = fma(s.y, w10, acc[i][0]);
                acc[i][1] = fma(s.y, w11, acc[i][1]);
                acc[i][2] = fma(s.y, w12, acc[i][2]);
                acc[i][3] = fma(s.y, w13, acc[i][3]);
            }
        }
        __syncthreads();
    }

    #pragma unroll
    for (int c = 0; c < 4; ++c) {
        int col = colb + tc + 32 * c;
        double bb = (double)bhh[col];
        #pragma unroll
        for (int i = 0; i < 8; ++i) {
            int r = rg * 8 + i;
            double e = (double)emb[(size_t)sd[r] * NH + col];
            double z = acc[i][c] + bb + e;
            states_out[(size_t)(rowb + r) * NH + col] = (float)tanh(z);
        }
    }
}

// ---------------- finalize: d_out = [hist as float (524288), scores as float (32768)]
__global__ void k_final(const int* __restrict__ hist, const double* __restrict__ scores,
                        float* __restrict__ out)
{
    int i = blockIdx.x * 256 + threadIdx.x;
    const int nh = BKROWS * NDEPTH;      // 524288
    if (i < nh) out[i] = (float)hist[i];
    else if (i < nh + BKROWS) out[i] = (float)scores[i - nh];
}

extern "C" void kernel_launch(void* const* d_in, const int* in_sizes, int n_in,
                              void* d_out, int out_size, void* d_ws, size_t ws_size,
                              hipStream_t stream) {
    // inputs: env(unused), root_state, W_logits, b_logits, W_hh, b_hh, emb, beams(=128)
    const float* root = (const float*)d_in[1];
    const float* Wl   = (const float*)d_in[2];
    const float* bl   = (const float*)d_in[3];
    const float* Whh  = (const float*)d_in[4];
    const float* bhh  = (const float*)d_in[5];
    const float* emb  = (const float*)d_in[6];

    char* ws = (char*)d_ws;
    double* cand   = (double*)(ws + 0);            // 16,777,216 B
    double* scores = (double*)(ws + 16777216);     //    262,144 B
    float*  sA     = (float*)(ws + 17039360);      // 67,108,864 B
    float*  sB     = (float*)(ws + 84148224);      // 67,108,864 B
    int*    parent = (int*)(ws + 151257088);       //    131,072 B
    int*    decs   = (int*)(ws + 151388160);       //    131,072 B
    int*    hA     = (int*)(ws + 151519232);       //  2,097,152 B
    int*    hB     = (int*)(ws + 153616384);       //  2,097,152 B

    k_init<<<65536, 256, 0, stream>>>(root, sA, scores, hA);

    float* scur = sA; float* snxt = sB;
    int*   hcur = hA; int*   hnxt = hB;
    for (int t = 0; t < NDEPTH; ++t) {
        k_logits<<<512, 256, 0, stream>>>(scur, Wl, bl, scores, cand);
        k_topk<<<256, 256, 0, stream>>>(cand, scores, parent, decs, hcur, hnxt, t);
        k_rnn<<<dim3(512, 4), 256, 0, stream>>>(scur, Whh, bhh, emb, parent, decs, snxt);
        { float* tmp = scur; scur = snxt; snxt = tmp; }
        { int*   tmp = hcur; hcur = hnxt; hnxt = tmp; }
    }

    k_final<<<2176, 256, 0, stream>>>(hcur, scores, (float*)d_out);
}